// Round 3
// baseline (367.168 us; speedup 1.0000x reference)
//
#include <hip/hip_runtime.h>
#include <hip/hip_bf16.h>

// GLM flash attention fwd: b=2, s=2048, nh=16, hs=64, fp32 I/O, bf16 MFMA.
// R11: no split-K, no atomics. R9/R10 counters showed 16.8M fp32 L2 atomic
// RMWs (WRITE_SIZE ~4x output size) congesting L2 and inflating all load
// latency; both structures were memory-system-queue-bound (~12K wave-cyc per
// chunk vs ~700 static). Now: one wave (64-thr block) owns 32 q-rows over the
// FULL k-range [0, klen), normalizes in-register, writes out once with plain
// stores. LPT block order (q0 descending, heads fastest) for load balance.
// K B-frags register-prefetched one chunk ahead (ping-pong, no dyn indexing);
// V frags issued at chunk top, consumed in PV. P tile stays in LDS (5KB,
// kh-double-buffered, one lgkm drain/chunk). 2 dispatches: conv_kv + fa.

typedef __attribute__((ext_vector_type(8))) __bf16 bf16x8;
typedef __attribute__((ext_vector_type(4))) __bf16 bf16x4;
typedef __attribute__((ext_vector_type(4))) float floatx4;

#define S_LEN 2048
#define NH 16
#define HS 64
#define RS 1024                     // fp32 floats between seq positions
#define KB_ELEMS (2 * NH * S_LEN * HS)   // 4,194,304 bf16 = 8 MB
#define SCALE_LOG2E 0.18033688011112042f // 0.125 / ln(2)

#if __has_builtin(__builtin_amdgcn_exp2f)
#define EXP2(x) __builtin_amdgcn_exp2f(x)
#else
#define EXP2(x) exp2f(x)
#endif

#define MFMA(a, b, c) __builtin_amdgcn_mfma_f32_16x16x32_bf16(a, b, c, 0, 0, 0)

// ---- pre-pass: K -> bf16 [b,h,s,d] (scaled), V -> bf16 V^T [b,h,d,s] ----
__global__ __launch_bounds__(256) void conv_kv(const float* __restrict__ k,
                                               const float* __restrict__ v,
                                               __bf16* __restrict__ kbuf,
                                               __bf16* __restrict__ vbuf)
{
    __shared__ __align__(16) __bf16 tile[64][72];     // [d][s], 144B rows
    const int tid = threadIdx.x;

    const int bh = blockIdx.x >> 5;                   // 32 s-tiles per (b,h)
    const int st = blockIdx.x & 31;
    const int b = bh >> 4, h = bh & 15;
    const int s0 = st * 64;

#pragma unroll
    for (int it = 0; it < 4; ++it) {
        const int idx = it * 256 + tid;
        const int s = idx >> 4, f4 = idx & 15;
        floatx4 val = *(const floatx4*)(k + ((size_t)(b * 2048 + s0 + s)) * 1024 + h * 64 + f4 * 4);
        bf16x4 w;
        w[0] = (__bf16)(val[0] * SCALE_LOG2E); w[1] = (__bf16)(val[1] * SCALE_LOG2E);
        w[2] = (__bf16)(val[2] * SCALE_LOG2E); w[3] = (__bf16)(val[3] * SCALE_LOG2E);
        *(bf16x4*)(kbuf + ((size_t)((b * 16 + h) * 2048 + s0 + s)) * 64 + f4 * 4) = w;
    }

#pragma unroll
    for (int it = 0; it < 4; ++it) {
        const int idx = it * 256 + tid;
        const int s = idx >> 4, f4 = idx & 15;
        floatx4 val = *(const floatx4*)(v + ((size_t)(b * 2048 + s0 + s)) * 1024 + h * 64 + f4 * 4);
#pragma unroll
        for (int i = 0; i < 4; ++i)
            tile[f4 * 4 + i][s] = (__bf16)val[i];
    }
    __syncthreads();
#pragma unroll
    for (int it = 0; it < 2; ++it) {
        const int idx = it * 256 + tid;
        const int d = idx >> 3, sg = idx & 7;
        bf16x8 w = *(const bf16x8*)&tile[d][sg * 8];
        *(bf16x8*)(vbuf + ((size_t)((b * 16 + h) * 64 + d)) * 2048 + s0 + sg * 8) = w;
    }
}

// One 64-col chunk: V loads at top, QK^T, K-prefetch for next chunk,
// exp/mask -> P tiles, one lgkm drain, PV. BC = current K frags, BN = next.
#define CHUNK_STEP(K0, BC, BN, PF)                                             \
  {                                                                            \
    const int k0_ = (K0);                                                      \
    /* V B-frags for this chunk (consumed at the end, in PV) */                \
    bf16x8 bv[4][2];                                                           \
    _Pragma("unroll")                                                          \
    for (int f = 0; f < 4; ++f)                                                \
      _Pragma("unroll")                                                        \
      for (int kh = 0; kh < 2; ++kh)                                           \
        bv[f][kh] = *(const bf16x8*)(vth + (size_t)(f * 16 + col) * 2048 +     \
                                     k0_ + kh * 32 + quad * 8);                \
    /* QK^T (K carries 0.125*log2e): 16 MFMAs */                               \
    floatx4 z_ = {0.f, 0.f, 0.f, 0.f};                                         \
    floatx4 s[2][4];                                                           \
    __builtin_amdgcn_s_setprio(1);                                             \
    _Pragma("unroll")                                                          \
    for (int rg = 0; rg < 2; ++rg)                                             \
      _Pragma("unroll")                                                        \
      for (int kg = 0; kg < 4; ++kg) {                                         \
        s[rg][kg] = MFMA(aq[rg][0], BC[kg][0], z_);                            \
        s[rg][kg] = MFMA(aq[rg][1], BC[kg][1], s[rg][kg]);                     \
      }                                                                        \
    __builtin_amdgcn_s_setprio(0);                                             \
    /* register-prefetch next chunk's K B-frags */                             \
    if (PF) {                                                                  \
      _Pragma("unroll")                                                        \
      for (int kg = 0; kg < 4; ++kg)                                           \
        _Pragma("unroll")                                                      \
        for (int hf = 0; hf < 2; ++hf)                                         \
          BN[kg][hf] = *(const bf16x8*)(kbh +                                  \
              (size_t)(k0_ + 64 + kg * 16 + col) * 64 + hf * 32 + quad * 8);   \
    }                                                                          \
    /* exp + mask -> both kh P tiles, then ONE lgkm drain */                   \
    _Pragma("unroll")                                                          \
    for (int kh = 0; kh < 2; ++kh) {                                           \
      _Pragma("unroll")                                                        \
      for (int rg = 0; rg < 2; ++rg) {                                         \
        __bf16* pw = &pt[kh][rg][0];                                           \
        _Pragma("unroll")                                                      \
        for (int g2 = 0; g2 < 2; ++g2) {                                       \
          const int kj = k0_ + (kh * 2 + g2) * 16 + col;                       \
          const bool pre = kj < bp;                                            \
          _Pragma("unroll")                                                    \
          for (int r = 0; r < 4; ++r) {                                        \
            const int qi = q0 + rg * 16 + quad * 4 + r;                        \
            float e = EXP2(s[rg][kh * 2 + g2][r]);                             \
            float p = (pre || (kj <= qi)) ? e : 0.f;                           \
            ls[rg][r] += p;                                                    \
            pw[(quad * 4 + r) * 40 + g2 * 16 + col] = (__bf16)p;               \
          }                                                                    \
        }                                                                      \
      }                                                                        \
    }                                                                          \
    __asm__ __volatile__("" ::: "memory");                                     \
    __builtin_amdgcn_s_waitcnt(0xC07F); /* lgkmcnt(0): P writes drained */     \
    __asm__ __volatile__("" ::: "memory");                                     \
    /* PV: 16 MFMAs */                                                         \
    __builtin_amdgcn_s_setprio(1);                                             \
    _Pragma("unroll")                                                          \
    for (int kh = 0; kh < 2; ++kh)                                             \
      _Pragma("unroll")                                                        \
      for (int rg = 0; rg < 2; ++rg) {                                         \
        bf16x8 ap = *(const bf16x8*)(&pt[kh][rg][0] + col * 40 + quad * 8);    \
        _Pragma("unroll")                                                      \
        for (int f = 0; f < 4; ++f)                                            \
          o[rg][f] = MFMA(ap, bv[f][kh], o[rg][f]);                            \
      }                                                                        \
    __builtin_amdgcn_s_setprio(0);                                             \
    __asm__ __volatile__("" ::: "memory"); /* next P writes stay behind ap */  \
  }

// ---- main kernel: 1 wave per block, 32 q-rows, full k-range, no atomics ----
__global__ __launch_bounds__(64, 4) void fa_part7(
    const float* __restrict__ q, const __bf16* __restrict__ kb,
    const __bf16* __restrict__ vt, const int* __restrict__ glm_mask,
    float* __restrict__ out)
{
    __shared__ __align__(16) __bf16 pt[2][2][16 * 40];  // 5120 B

    const int lane = threadIdx.x;                 // one wave per block
    const int col  = lane & 15, quad = lane >> 4;

    // LPT order: longest q-tiles first (q0 descending), heads fastest
    const int tile = blockIdx.x >> 5;             // 0..63
    const int head = blockIdx.x & 31;
    const int b = head >> 4, h = head & 15;
    const int q0 = (63 - tile) * 32;              // this wave's 32 q-rows

    const int bp = glm_mask[b];
    int klen = q0 + 32; if (bp > klen) klen = bp;
    const int nch = (klen + 63) >> 6;             // >= 1 always

    const __bf16* kbh = kb + ((size_t)(b * 16 + h)) * (2048 * 64);
    const __bf16* vth = vt + ((size_t)(b * 16 + h)) * (64 * 2048);
    const size_t obase = (size_t)b * (S_LEN * RS) + h * HS;

    // Q A-frags: aq[rg][half], kd = half*32 + quad*8 + j
    bf16x8 aq[2][2];
#pragma unroll
    for (int rg = 0; rg < 2; ++rg) {
        const float* qp = q + obase + (size_t)(q0 + rg * 16 + col) * RS + quad * 8;
        floatx4 a0 = *(const floatx4*)qp;
        floatx4 a1 = *(const floatx4*)(qp + 4);
        floatx4 a2 = *(const floatx4*)(qp + 32);
        floatx4 a3 = *(const floatx4*)(qp + 36);
#pragma unroll
        for (int i = 0; i < 4; ++i) {
            aq[rg][0][i] = (__bf16)a0[i]; aq[rg][0][4 + i] = (__bf16)a1[i];
            aq[rg][1][i] = (__bf16)a2[i]; aq[rg][1][4 + i] = (__bf16)a3[i];
        }
    }

    floatx4 o[2][4];                // O C-frags: row = q0+rg*16+quad*4+r, d = f*16+col
    float ls[2][4];
#pragma unroll
    for (int rg = 0; rg < 2; ++rg)
#pragma unroll
        for (int f = 0; f < 4; ++f) {
            o[rg][f] = (floatx4){0.f, 0.f, 0.f, 0.f};
            ls[rg][f] = 0.f;
        }

    // preload chunk 0's K frags
    bf16x8 bkA[4][2], bkB[4][2];
#pragma unroll
    for (int kg = 0; kg < 4; ++kg)
#pragma unroll
        for (int hf = 0; hf < 2; ++hf)
            bkA[kg][hf] = *(const bf16x8*)(kbh + (size_t)(kg * 16 + col) * 64 + hf * 32 + quad * 8);

    // ping-pong over chunks, 2 per iteration
    int c = 0;
    for (; c + 1 < nch; c += 2) {
        CHUNK_STEP(c * 64,       bkA, bkB, true);
        CHUNK_STEP((c + 1) * 64, bkB, bkA, (c + 2 < nch));
    }
    if (c < nch)
        CHUNK_STEP(c * 64, bkA, bkB, false);

    // epilogue: reduce l across the 16 col-lanes, normalize, plain stores
#pragma unroll
    for (int rg = 0; rg < 2; ++rg)
#pragma unroll
        for (int r = 0; r < 4; ++r) {
            float l = ls[rg][r];
            l += __shfl_xor(l, 1);
            l += __shfl_xor(l, 2);
            l += __shfl_xor(l, 4);
            l += __shfl_xor(l, 8);
            const float inv = (l > 0.f) ? (1.f / l) : 0.f;
            const int row = q0 + rg * 16 + quad * 4 + r;
            float* op = out + obase + (size_t)row * RS;
#pragma unroll
            for (int f = 0; f < 4; ++f)
                op[f * 16 + col] = o[rg][f][r] * inv;
        }
}

extern "C" void kernel_launch(void* const* d_in, const int* in_sizes, int n_in,
                              void* d_out, int out_size, void* d_ws, size_t ws_size,
                              hipStream_t stream) {
    const float* q = (const float*)d_in[0];
    const float* k = (const float*)d_in[1];
    const float* v = (const float*)d_in[2];
    const int* glm = (const int*)d_in[3];
    float* out     = (float*)d_out;

    const size_t kb_bytes = (size_t)KB_ELEMS * 2;            // 8 MB
    __bf16* kbuf = (__bf16*)d_ws;
    __bf16* vbuf = (__bf16*)((char*)d_ws + kb_bytes);

    hipLaunchKernelGGL(conv_kv, dim3(1024), dim3(256), 0, stream,
                       k, v, kbuf, vbuf);
    // 64 q-tiles (LPT order) x 32 heads = 2048 one-wave blocks
    hipLaunchKernelGGL(fa_part7, dim3(2048), dim3(64), 0, stream,
                       q, kbuf, vbuf, glm, out);
}

// Round 4
// 190.392 us; speedup vs baseline: 1.9285x; 1.9285x over previous
//
#include <hip/hip_runtime.h>
#include <hip/hip_bf16.h>

// GLM flash attention fwd: b=2, s=2048, nh=16, hs=64, fp32 I/O, bf16 MFMA.
// R12 = R11 with the spill fixed. R11's __launch_bounds__(64,4) capped VGPRs
// at 64 while the kernel needs ~210 -> everything spilled (WRITE_SIZE 705MB
// vs 16MB output, VGPR_Count=64, 289us). Now __launch_bounds__(64,2): cap
// 256 VGPRs, 2 waves/SIMD, 8 blocks/CU -> all 2048 one-wave blocks resident,
// zero scratch. Structure unchanged: no split-K, no atomics; one wave owns
// 32 q-rows over the full k-range, normalizes in-register, single plain
// store of out. LPT block order (q0 descending, heads fastest). K B-frags
// register-prefetched one chunk ahead (ping-pong); V frags at chunk top.
// P tile in LDS (5KB, kh-double-buffered, one lgkm drain/chunk).

typedef __attribute__((ext_vector_type(8))) __bf16 bf16x8;
typedef __attribute__((ext_vector_type(4))) __bf16 bf16x4;
typedef __attribute__((ext_vector_type(4))) float floatx4;

#define S_LEN 2048
#define NH 16
#define HS 64
#define RS 1024                     // fp32 floats between seq positions
#define KB_ELEMS (2 * NH * S_LEN * HS)   // 4,194,304 bf16 = 8 MB
#define SCALE_LOG2E 0.18033688011112042f // 0.125 / ln(2)

#if __has_builtin(__builtin_amdgcn_exp2f)
#define EXP2(x) __builtin_amdgcn_exp2f(x)
#else
#define EXP2(x) exp2f(x)
#endif

#define MFMA(a, b, c) __builtin_amdgcn_mfma_f32_16x16x32_bf16(a, b, c, 0, 0, 0)

// ---- pre-pass: K -> bf16 [b,h,s,d] (scaled), V -> bf16 V^T [b,h,d,s] ----
__global__ __launch_bounds__(256) void conv_kv(const float* __restrict__ k,
                                               const float* __restrict__ v,
                                               __bf16* __restrict__ kbuf,
                                               __bf16* __restrict__ vbuf)
{
    __shared__ __align__(16) __bf16 tile[64][72];     // [d][s], 144B rows
    const int tid = threadIdx.x;

    const int bh = blockIdx.x >> 5;                   // 32 s-tiles per (b,h)
    const int st = blockIdx.x & 31;
    const int b = bh >> 4, h = bh & 15;
    const int s0 = st * 64;

#pragma unroll
    for (int it = 0; it < 4; ++it) {
        const int idx = it * 256 + tid;
        const int s = idx >> 4, f4 = idx & 15;
        floatx4 val = *(const floatx4*)(k + ((size_t)(b * 2048 + s0 + s)) * 1024 + h * 64 + f4 * 4);
        bf16x4 w;
        w[0] = (__bf16)(val[0] * SCALE_LOG2E); w[1] = (__bf16)(val[1] * SCALE_LOG2E);
        w[2] = (__bf16)(val[2] * SCALE_LOG2E); w[3] = (__bf16)(val[3] * SCALE_LOG2E);
        *(bf16x4*)(kbuf + ((size_t)((b * 16 + h) * 2048 + s0 + s)) * 64 + f4 * 4) = w;
    }

#pragma unroll
    for (int it = 0; it < 4; ++it) {
        const int idx = it * 256 + tid;
        const int s = idx >> 4, f4 = idx & 15;
        floatx4 val = *(const floatx4*)(v + ((size_t)(b * 2048 + s0 + s)) * 1024 + h * 64 + f4 * 4);
#pragma unroll
        for (int i = 0; i < 4; ++i)
            tile[f4 * 4 + i][s] = (__bf16)val[i];
    }
    __syncthreads();
#pragma unroll
    for (int it = 0; it < 2; ++it) {
        const int idx = it * 256 + tid;
        const int d = idx >> 3, sg = idx & 7;
        bf16x8 w = *(const bf16x8*)&tile[d][sg * 8];
        *(bf16x8*)(vbuf + ((size_t)((b * 16 + h) * 64 + d)) * 2048 + s0 + sg * 8) = w;
    }
}

// One 64-col chunk: V loads at top, QK^T, K-prefetch for next chunk,
// exp/mask -> P tiles, one lgkm drain, PV. BC = current K frags, BN = next.
#define CHUNK_STEP(K0, BC, BN, PF)                                             \
  {                                                                            \
    const int k0_ = (K0);                                                      \
    /* V B-frags for this chunk (consumed at the end, in PV) */                \
    bf16x8 bv[4][2];                                                           \
    _Pragma("unroll")                                                          \
    for (int f = 0; f < 4; ++f)                                                \
      _Pragma("unroll")                                                        \
      for (int kh = 0; kh < 2; ++kh)                                           \
        bv[f][kh] = *(const bf16x8*)(vth + (size_t)(f * 16 + col) * 2048 +     \
                                     k0_ + kh * 32 + quad * 8);                \
    /* QK^T (K carries 0.125*log2e): 16 MFMAs */                               \
    floatx4 z_ = {0.f, 0.f, 0.f, 0.f};                                         \
    floatx4 s[2][4];                                                           \
    __builtin_amdgcn_s_setprio(1);                                             \
    _Pragma("unroll")                                                          \
    for (int rg = 0; rg < 2; ++rg)                                             \
      _Pragma("unroll")                                                        \
      for (int kg = 0; kg < 4; ++kg) {                                         \
        s[rg][kg] = MFMA(aq[rg][0], BC[kg][0], z_);                            \
        s[rg][kg] = MFMA(aq[rg][1], BC[kg][1], s[rg][kg]);                     \
      }                                                                        \
    __builtin_amdgcn_s_setprio(0);                                             \
    /* register-prefetch next chunk's K B-frags */                             \
    if (PF) {                                                                  \
      _Pragma("unroll")                                                        \
      for (int kg = 0; kg < 4; ++kg)                                           \
        _Pragma("unroll")                                                      \
        for (int hf = 0; hf < 2; ++hf)                                         \
          BN[kg][hf] = *(const bf16x8*)(kbh +                                  \
              (size_t)(k0_ + 64 + kg * 16 + col) * 64 + hf * 32 + quad * 8);   \
    }                                                                          \
    /* exp + mask -> both kh P tiles, then ONE lgkm drain */                   \
    _Pragma("unroll")                                                          \
    for (int kh = 0; kh < 2; ++kh) {                                           \
      _Pragma("unroll")                                                        \
      for (int rg = 0; rg < 2; ++rg) {                                         \
        __bf16* pw = &pt[kh][rg][0];                                           \
        _Pragma("unroll")                                                      \
        for (int g2 = 0; g2 < 2; ++g2) {                                       \
          const int kj = k0_ + (kh * 2 + g2) * 16 + col;                       \
          const bool pre = kj < bp;                                            \
          _Pragma("unroll")                                                    \
          for (int r = 0; r < 4; ++r) {                                        \
            const int qi = q0 + rg * 16 + quad * 4 + r;                        \
            float e = EXP2(s[rg][kh * 2 + g2][r]);                             \
            float p = (pre || (kj <= qi)) ? e : 0.f;                           \
            ls[rg][r] += p;                                                    \
            pw[(quad * 4 + r) * 40 + g2 * 16 + col] = (__bf16)p;               \
          }                                                                    \
        }                                                                      \
      }                                                                        \
    }                                                                          \
    __asm__ __volatile__("" ::: "memory");                                     \
    __builtin_amdgcn_s_waitcnt(0xC07F); /* lgkmcnt(0): P writes drained */     \
    __asm__ __volatile__("" ::: "memory");                                     \
    /* PV: 16 MFMAs */                                                         \
    __builtin_amdgcn_s_setprio(1);                                             \
    _Pragma("unroll")                                                          \
    for (int kh = 0; kh < 2; ++kh)                                             \
      _Pragma("unroll")                                                        \
      for (int rg = 0; rg < 2; ++rg) {                                         \
        bf16x8 ap = *(const bf16x8*)(&pt[kh][rg][0] + col * 40 + quad * 8);    \
        _Pragma("unroll")                                                      \
        for (int f = 0; f < 4; ++f)                                            \
          o[rg][f] = MFMA(ap, bv[f][kh], o[rg][f]);                            \
      }                                                                        \
    __builtin_amdgcn_s_setprio(0);                                             \
    __asm__ __volatile__("" ::: "memory"); /* next P writes stay behind ap */  \
  }

// ---- main kernel: 1 wave per block, 32 q-rows, full k-range, no atomics ----
__global__ __launch_bounds__(64, 2) void fa_part7(
    const float* __restrict__ q, const __bf16* __restrict__ kb,
    const __bf16* __restrict__ vt, const int* __restrict__ glm_mask,
    float* __restrict__ out)
{
    __shared__ __align__(16) __bf16 pt[2][2][16 * 40];  // 5120 B

    const int lane = threadIdx.x;                 // one wave per block
    const int col  = lane & 15, quad = lane >> 4;

    // LPT order: longest q-tiles first (q0 descending), heads fastest
    const int tile = blockIdx.x >> 5;             // 0..63
    const int head = blockIdx.x & 31;
    const int b = head >> 4, h = head & 15;
    const int q0 = (63 - tile) * 32;              // this wave's 32 q-rows

    const int bp = glm_mask[b];
    int klen = q0 + 32; if (bp > klen) klen = bp;
    const int nch = (klen + 63) >> 6;             // >= 1 always

    const __bf16* kbh = kb + ((size_t)(b * 16 + h)) * (2048 * 64);
    const __bf16* vth = vt + ((size_t)(b * 16 + h)) * (64 * 2048);
    const size_t obase = (size_t)b * (S_LEN * RS) + h * HS;

    // Q A-frags: aq[rg][half], kd = half*32 + quad*8 + j
    bf16x8 aq[2][2];
#pragma unroll
    for (int rg = 0; rg < 2; ++rg) {
        const float* qp = q + obase + (size_t)(q0 + rg * 16 + col) * RS + quad * 8;
        floatx4 a0 = *(const floatx4*)qp;
        floatx4 a1 = *(const floatx4*)(qp + 4);
        floatx4 a2 = *(const floatx4*)(qp + 32);
        floatx4 a3 = *(const floatx4*)(qp + 36);
#pragma unroll
        for (int i = 0; i < 4; ++i) {
            aq[rg][0][i] = (__bf16)a0[i]; aq[rg][0][4 + i] = (__bf16)a1[i];
            aq[rg][1][i] = (__bf16)a2[i]; aq[rg][1][4 + i] = (__bf16)a3[i];
        }
    }

    floatx4 o[2][4];                // O C-frags: row = q0+rg*16+quad*4+r, d = f*16+col
    float ls[2][4];
#pragma unroll
    for (int rg = 0; rg < 2; ++rg)
#pragma unroll
        for (int f = 0; f < 4; ++f) {
            o[rg][f] = (floatx4){0.f, 0.f, 0.f, 0.f};
            ls[rg][f] = 0.f;
        }

    // preload chunk 0's K frags
    bf16x8 bkA[4][2], bkB[4][2];
#pragma unroll
    for (int kg = 0; kg < 4; ++kg)
#pragma unroll
        for (int hf = 0; hf < 2; ++hf)
            bkA[kg][hf] = *(const bf16x8*)(kbh + (size_t)(kg * 16 + col) * 64 + hf * 32 + quad * 8);

    // ping-pong over chunks, 2 per iteration
    int c = 0;
    for (; c + 1 < nch; c += 2) {
        CHUNK_STEP(c * 64,       bkA, bkB, true);
        CHUNK_STEP((c + 1) * 64, bkB, bkA, (c + 2 < nch));
    }
    if (c < nch)
        CHUNK_STEP(c * 64, bkA, bkB, false);

    // epilogue: reduce l across the 16 col-lanes, normalize, plain stores
#pragma unroll
    for (int rg = 0; rg < 2; ++rg)
#pragma unroll
        for (int r = 0; r < 4; ++r) {
            float l = ls[rg][r];
            l += __shfl_xor(l, 1);
            l += __shfl_xor(l, 2);
            l += __shfl_xor(l, 4);
            l += __shfl_xor(l, 8);
            const float inv = (l > 0.f) ? (1.f / l) : 0.f;
            const int row = q0 + rg * 16 + quad * 4 + r;
            float* op = out + obase + (size_t)row * RS;
#pragma unroll
            for (int f = 0; f < 4; ++f)
                op[f * 16 + col] = o[rg][f][r] * inv;
        }
}

extern "C" void kernel_launch(void* const* d_in, const int* in_sizes, int n_in,
                              void* d_out, int out_size, void* d_ws, size_t ws_size,
                              hipStream_t stream) {
    const float* q = (const float*)d_in[0];
    const float* k = (const float*)d_in[1];
    const float* v = (const float*)d_in[2];
    const int* glm = (const int*)d_in[3];
    float* out     = (float*)d_out;

    const size_t kb_bytes = (size_t)KB_ELEMS * 2;            // 8 MB
    __bf16* kbuf = (__bf16*)d_ws;
    __bf16* vbuf = (__bf16*)((char*)d_ws + kb_bytes);

    hipLaunchKernelGGL(conv_kv, dim3(1024), dim3(256), 0, stream,
                       k, v, kbuf, vbuf);
    // 64 q-tiles (LPT order) x 32 heads = 2048 one-wave blocks
    hipLaunchKernelGGL(fa_part7, dim3(2048), dim3(64), 0, stream,
                       q, kbuf, vbuf, glm, out);
}